// Round 5
// baseline (658.258 us; speedup 1.0000x reference)
//
#include <hip/hip_runtime.h>

#define NN 50000
#define NE 800000

// ---------------- CSR build ----------------

__global__ void k_count(const int* __restrict__ dst, int* __restrict__ cnt, int E) {
    int e = blockIdx.x * 256 + threadIdx.x;
    if (e < E) atomicAdd(&cnt[dst[e]], 1);
}

__global__ void k_dinv(const int* __restrict__ cnt, float* __restrict__ dinv, int N) {
    int i = blockIdx.x * 256 + threadIdx.x;
    if (i < N) dinv[i] = rsqrtf(2.0f + (float)cnt[i]);
}

// phase A: per-block (256-wide) scan; row_ptr[i] = local exclusive, bsum[b] = block total
__global__ void k_scanA(const int* __restrict__ cnt, int* __restrict__ row_ptr,
                        int* __restrict__ bsum, int N) {
    __shared__ int buf[256];
    int i = blockIdx.x * 256 + threadIdx.x;
    int v = (i < N) ? cnt[i] : 0;
    buf[threadIdx.x] = v;
    __syncthreads();
    for (int off = 1; off < 256; off <<= 1) {
        int t = (threadIdx.x >= off) ? buf[threadIdx.x - off] : 0;
        __syncthreads();
        buf[threadIdx.x] += t;
        __syncthreads();
    }
    if (i < N) row_ptr[i] = buf[threadIdx.x] - v;   // local exclusive
    if (threadIdx.x == 255) bsum[blockIdx.x] = buf[255];
}

// phase B: single-block exclusive scan of block sums (nb <= 256)
__global__ void k_scanB(int* __restrict__ bsum, int nb) {
    __shared__ int buf[256];
    int v = (threadIdx.x < nb) ? bsum[threadIdx.x] : 0;
    buf[threadIdx.x] = v;
    __syncthreads();
    for (int off = 1; off < 256; off <<= 1) {
        int t = (threadIdx.x >= off) ? buf[threadIdx.x - off] : 0;
        __syncthreads();
        buf[threadIdx.x] += t;
        __syncthreads();
    }
    if (threadIdx.x < nb) bsum[threadIdx.x] = buf[threadIdx.x] - v;  // exclusive
}

// phase C: add block offsets; set row_ptr[N] = E
__global__ void k_scanC(int* __restrict__ row_ptr, const int* __restrict__ bsum,
                        int N, int E) {
    int i = blockIdx.x * 256 + threadIdx.x;
    if (i < N) row_ptr[i] += bsum[blockIdx.x];
    if (i == 0) row_ptr[N] = E;
}

// packed (src, norm-bits) single 8B scatter (R2->R3: WRITE 83->53MB)
__global__ void k_fill(const int* __restrict__ src, const int* __restrict__ dst,
                       const float* __restrict__ dinv, const int* __restrict__ row_ptr,
                       int* __restrict__ cursor, int2* __restrict__ csr, int E) {
    int e = blockIdx.x * 256 + threadIdx.x;
    if (e >= E) return;
    int s = src[e], d = dst[e];
    int pos = row_ptr[d] + atomicAdd(&cursor[d], 1);
    float nm = dinv[s] * dinv[d];
    csr[pos] = make_int2(s, __float_as_int(nm));
}

// ---------------- GEMM: H = X @ W  (X: [N,K], W: [K,64], H: [N,64]) ----------------
// #pragma unroll 1: without it the compiler fully unrolls, blows the VGPR
// budget and spills ~230MB scratch (R1: VGPR=256, FETCH 117MB, WRITE 128MB).

template <int K>
__global__ __launch_bounds__(256, 4) void k_gemm(const float* __restrict__ X,
                                                 const float* __restrict__ W,
                                                 float* __restrict__ H, int N) {
    __shared__ float Ws[K * 64];
    for (int i = threadIdx.x; i < K * 16; i += 256)
        ((float4*)Ws)[i] = ((const float4*)W)[i];
    __syncthreads();

    const int g  = threadIdx.x >> 3;
    const int c0 = (threadIdx.x & 7) * 8;
    const int r0 = blockIdx.x * 64 + g * 2;
    const int r1 = r0 + 1;
    const bool v0 = r0 < N, v1 = r1 < N;

    float a00=0,a01=0,a02=0,a03=0,a04=0,a05=0,a06=0,a07=0;
    float a10=0,a11=0,a12=0,a13=0,a14=0,a15=0,a16=0,a17=0;

    const float* x0 = X + (size_t)r0 * K;
    const float* x1 = X + (size_t)r1 * K;

#pragma unroll 1
    for (int k0 = 0; k0 < K; k0 += 4) {
        float4 xa = v0 ? *(const float4*)(x0 + k0) : make_float4(0, 0, 0, 0);
        float4 xb = v1 ? *(const float4*)(x1 + k0) : make_float4(0, 0, 0, 0);
#pragma unroll
        for (int kk = 0; kk < 4; ++kk) {
            const float xs0 = (kk == 0) ? xa.x : (kk == 1) ? xa.y : (kk == 2) ? xa.z : xa.w;
            const float xs1 = (kk == 0) ? xb.x : (kk == 1) ? xb.y : (kk == 2) ? xb.z : xb.w;
            const float* wr = &Ws[(k0 + kk) * 64 + c0];
            const float4 w0 = *(const float4*)(wr);
            const float4 w1 = *(const float4*)(wr + 4);
            a00 = fmaf(xs0, w0.x, a00); a01 = fmaf(xs0, w0.y, a01);
            a02 = fmaf(xs0, w0.z, a02); a03 = fmaf(xs0, w0.w, a03);
            a04 = fmaf(xs0, w1.x, a04); a05 = fmaf(xs0, w1.y, a05);
            a06 = fmaf(xs0, w1.z, a06); a07 = fmaf(xs0, w1.w, a07);
            a10 = fmaf(xs1, w0.x, a10); a11 = fmaf(xs1, w0.y, a11);
            a12 = fmaf(xs1, w0.z, a12); a13 = fmaf(xs1, w0.w, a13);
            a14 = fmaf(xs1, w1.x, a14); a15 = fmaf(xs1, w1.y, a15);
            a16 = fmaf(xs1, w1.z, a16); a17 = fmaf(xs1, w1.w, a17);
        }
    }

    if (v0) {
        *(float4*)&H[(size_t)r0 * 64 + c0]     = make_float4(a00, a01, a02, a03);
        *(float4*)&H[(size_t)r0 * 64 + c0 + 4] = make_float4(a04, a05, a06, a07);
    }
    if (v1) {
        *(float4*)&H[(size_t)r1 * 64 + c0]     = make_float4(a10, a11, a12, a13);
        *(float4*)&H[(size_t)r1 * 64 + c0 + 4] = make_float4(a14, a15, a16, a17);
    }
}

// ---------------- Channel-sliced aggregation ----------------
// out[i, ch] = sum_e H[src_e, ch]*norm_e + 2*dinv[i]^2*H[i, ch] + b[ch]
//
// R4 diagnosis: dense-row gathers (256B/edge) make every XCD's L2 re-fetch
// the whole 12.8MB H (FETCH 83.5MB, ~900cy HBM misses, 52.5us). Fix: each
// block handles a 16-channel slice (64B = exactly one line per edge-row);
// slice = bid & 3. Under round-robin bid->XCD, slice s lands on XCDs {s,s+4},
// whose L2 only needs 50000 x 64B = 3.2MB of H -> resident, gathers become
// ~200cy L2 hits. csr is re-streamed 4x -> nontemporal loads so the stream
// doesn't evict the H slice.
//
// Wave layout: 4 edge-slots (g = lane>>4) x 16 channels (c = lane&15).

template <bool RELU>
__global__ __launch_bounds__(256, 8) void k_aggs(const float* __restrict__ H,
                                                 const int* __restrict__ row_ptr,
                                                 const int2* __restrict__ csr,
                                                 const float* __restrict__ dinv,
                                                 const float* __restrict__ bias,
                                                 float* __restrict__ out, int N) {
    const int slice = blockIdx.x & 3;
    const int wid   = threadIdx.x >> 6;
    const int lane  = threadIdx.x & 63;
    const int i     = (blockIdx.x >> 2) * 4 + wid;
    if (i >= N) return;

    const int g  = lane >> 4;              // edge sub-slot 0..3
    const int c  = lane & 15;              // channel within slice
    const int ch = slice * 16 + c;         // absolute channel

    const long long* csr_ll = (const long long*)csr;

    float acc = 0.0f;
    int start = row_ptr[i], end = row_ptr[i + 1];
    for (int base = start; base < end; base += 64) {
        int e = base + lane;
        long long pk = (e < end) ? __builtin_nontemporal_load(csr_ll + e) : 0LL;
        int px = (int)(pk & 0xffffffffLL);          // src
        int py = (int)(pk >> 32);                   // norm bits (0 -> 0.0f)
        int m  = end - base; if (m > 64) m = 64;
        int nt = (m + 3) >> 2;
#pragma unroll 4
        for (int t = 0; t < nt; ++t) {
            int sl   = t * 4 + g;
            int ss   = __shfl(px, sl);
            float nn = __uint_as_float(__shfl(py, sl));
            acc = fmaf(H[(size_t)ss * 64 + ch], nn, acc);
        }
    }

    // reduce the 4 edge-slot groups (lane bits 4,5)
    acc += __shfl_xor(acc, 16);
    acc += __shfl_xor(acc, 32);

    float di = dinv[i];
    float r  = acc + 2.0f * di * di * H[(size_t)i * 64 + ch] + bias[ch];
    if (RELU) r = fmaxf(r, 0.0f);
    if (g == 0)   // 16 lanes write one full 64B line
        out[(size_t)i * 64 + ch] = r;
}

// ---------------- launch ----------------

extern "C" void kernel_launch(void* const* d_in, const int* in_sizes, int n_in,
                              void* d_out, int out_size, void* d_ws, size_t ws_size,
                              hipStream_t stream) {
    (void)in_sizes; (void)n_in; (void)out_size; (void)ws_size;

    const float* x  = (const float*)d_in[0];
    const int*   ei = (const int*)d_in[1];
    const float* Wl[5] = {(const float*)d_in[2], (const float*)d_in[4], (const float*)d_in[6],
                          (const float*)d_in[8], (const float*)d_in[10]};
    const float* bl[5] = {(const float*)d_in[3], (const float*)d_in[5], (const float*)d_in[7],
                          (const float*)d_in[9], (const float*)d_in[11]};
    float* out = (float*)d_out;

    const int* src = ei;
    const int* dst = ei + NE;

    char* ws = (char*)d_ws;
    size_t off = 0;
    auto alloc = [&](size_t bytes) -> void* {
        void* p = ws + off;
        off += (bytes + 255) & ~(size_t)255;
        return p;
    };
    int*   cnt      = (int*)alloc(NN * 4);
    int*   row_ptr  = (int*)alloc((NN + 1) * 4);
    int*   cursor   = (int*)alloc(NN * 4);
    int*   bsum     = (int*)alloc(256 * 4);
    float* dinv     = (float*)alloc(NN * 4);
    int2*  csr      = (int2*)alloc((size_t)NE * 8);
    float* Hb       = (float*)alloc((size_t)NN * 64 * 4);
    float* Ab       = (float*)alloc((size_t)NN * 64 * 4);

    hipMemsetAsync(cnt, 0, NN * 4, stream);
    hipMemsetAsync(cursor, 0, NN * 4, stream);

    int ebl = (NE + 255) / 256;
    int nbl = (NN + 255) / 256;
    k_count<<<ebl, 256, 0, stream>>>(dst, cnt, NE);
    k_dinv<<<nbl, 256, 0, stream>>>(cnt, dinv, NN);
    k_scanA<<<nbl, 256, 0, stream>>>(cnt, row_ptr, bsum, NN);
    k_scanB<<<1, 256, 0, stream>>>(bsum, nbl);
    k_scanC<<<nbl, 256, 0, stream>>>(row_ptr, bsum, NN, NE);
    k_fill<<<ebl, 256, 0, stream>>>(src, dst, dinv, row_ptr, cursor, csr, NE);

    int gg = (NN + 63) / 64;                 // gemm grid
    int ga = 4 * ((NN + 3) / 4);             // agg grid: 4 slices x node-chunks

    // layer 1 (K=128)
    k_gemm<128><<<gg, 256, 0, stream>>>(x, Wl[0], Hb, NN);
    k_aggs<true><<<ga, 256, 0, stream>>>(Hb, row_ptr, csr, dinv, bl[0], Ab, NN);
    // layers 2-4 (K=64, ReLU)
    k_gemm<64><<<gg, 256, 0, stream>>>(Ab, Wl[1], Hb, NN);
    k_aggs<true><<<ga, 256, 0, stream>>>(Hb, row_ptr, csr, dinv, bl[1], Ab, NN);
    k_gemm<64><<<gg, 256, 0, stream>>>(Ab, Wl[2], Hb, NN);
    k_aggs<true><<<ga, 256, 0, stream>>>(Hb, row_ptr, csr, dinv, bl[2], Ab, NN);
    k_gemm<64><<<gg, 256, 0, stream>>>(Ab, Wl[3], Hb, NN);
    k_aggs<true><<<ga, 256, 0, stream>>>(Hb, row_ptr, csr, dinv, bl[3], Ab, NN);
    // layer 5 (no ReLU) -> d_out
    k_gemm<64><<<gg, 256, 0, stream>>>(Ab, Wl[4], Hb, NN);
    k_aggs<false><<<ga, 256, 0, stream>>>(Hb, row_ptr, csr, dinv, bl[4], out, NN);
}

// Round 6
// 335.485 us; speedup vs baseline: 1.9621x; 1.9621x over previous
//
#include <hip/hip_runtime.h>

#define NN 50000
#define NE 800000

// ---- bf16 helpers (bit ops; bf16->f32 is a 16-bit shift) ----
__device__ __forceinline__ float bf2f(unsigned short u) {
    union { unsigned int i; float f; } v; v.i = ((unsigned int)u) << 16; return v.f;
}
__device__ __forceinline__ unsigned short f2bf(float f) {
    union { float f; unsigned int i; } v; v.f = f;
    unsigned int r = v.i + 0x7fffu + ((v.i >> 16) & 1u);   // round-to-nearest-even
    return (unsigned short)(r >> 16);
}

// ---------------- CSR build ----------------

__global__ void k_count(const int* __restrict__ dst, int* __restrict__ cnt, int E) {
    int e = blockIdx.x * 256 + threadIdx.x;
    if (e < E) atomicAdd(&cnt[dst[e]], 1);
}

__global__ void k_dinv(const int* __restrict__ cnt, float* __restrict__ dinv, int N) {
    int i = blockIdx.x * 256 + threadIdx.x;
    if (i < N) dinv[i] = rsqrtf(2.0f + (float)cnt[i]);
}

__global__ void k_scanA(const int* __restrict__ cnt, int* __restrict__ row_ptr,
                        int* __restrict__ bsum, int N) {
    __shared__ int buf[256];
    int i = blockIdx.x * 256 + threadIdx.x;
    int v = (i < N) ? cnt[i] : 0;
    buf[threadIdx.x] = v;
    __syncthreads();
    for (int off = 1; off < 256; off <<= 1) {
        int t = (threadIdx.x >= off) ? buf[threadIdx.x - off] : 0;
        __syncthreads();
        buf[threadIdx.x] += t;
        __syncthreads();
    }
    if (i < N) row_ptr[i] = buf[threadIdx.x] - v;
    if (threadIdx.x == 255) bsum[blockIdx.x] = buf[255];
}

__global__ void k_scanB(int* __restrict__ bsum, int nb) {
    __shared__ int buf[256];
    int v = (threadIdx.x < nb) ? bsum[threadIdx.x] : 0;
    buf[threadIdx.x] = v;
    __syncthreads();
    for (int off = 1; off < 256; off <<= 1) {
        int t = (threadIdx.x >= off) ? buf[threadIdx.x - off] : 0;
        __syncthreads();
        buf[threadIdx.x] += t;
        __syncthreads();
    }
    if (threadIdx.x < nb) bsum[threadIdx.x] = buf[threadIdx.x] - v;
}

__global__ void k_scanC(int* __restrict__ row_ptr, const int* __restrict__ bsum,
                        int N, int E) {
    int i = blockIdx.x * 256 + threadIdx.x;
    if (i < N) row_ptr[i] += bsum[blockIdx.x];
    if (i == 0) row_ptr[N] = E;
}

__global__ void k_fill(const int* __restrict__ src, const int* __restrict__ dst,
                       const float* __restrict__ dinv, const int* __restrict__ row_ptr,
                       int* __restrict__ cursor, int2* __restrict__ csr, int E) {
    int e = blockIdx.x * 256 + threadIdx.x;
    if (e >= E) return;
    int s = src[e], d = dst[e];
    int pos = row_ptr[d] + atomicAdd(&cursor[d], 1);
    float nm = dinv[s] * dinv[d];
    csr[pos] = make_int2(s, __float_as_int(nm));
}

// ---------------- GEMM layer 1: H = X @ W1 -> bf16 H ----------------
// #pragma unroll 1: full unroll spills ~230MB scratch (R1).

__global__ __launch_bounds__(256, 4) void k_gemm128(const float* __restrict__ X,
                                                    const float* __restrict__ W,
                                                    unsigned short* __restrict__ H, int N) {
    const int K = 128;
    __shared__ float Ws[K * 64];
    for (int i = threadIdx.x; i < K * 16; i += 256)
        ((float4*)Ws)[i] = ((const float4*)W)[i];
    __syncthreads();

    const int g  = threadIdx.x >> 3;
    const int c0 = (threadIdx.x & 7) * 8;
    const int r0 = blockIdx.x * 64 + g * 2;
    const int r1 = r0 + 1;
    const bool v0 = r0 < N, v1 = r1 < N;

    float a00=0,a01=0,a02=0,a03=0,a04=0,a05=0,a06=0,a07=0;
    float a10=0,a11=0,a12=0,a13=0,a14=0,a15=0,a16=0,a17=0;

    const float* x0 = X + (size_t)r0 * K;
    const float* x1 = X + (size_t)r1 * K;

#pragma unroll 1
    for (int k0 = 0; k0 < K; k0 += 4) {
        float4 xa = v0 ? *(const float4*)(x0 + k0) : make_float4(0, 0, 0, 0);
        float4 xb = v1 ? *(const float4*)(x1 + k0) : make_float4(0, 0, 0, 0);
#pragma unroll
        for (int kk = 0; kk < 4; ++kk) {
            const float xs0 = (kk == 0) ? xa.x : (kk == 1) ? xa.y : (kk == 2) ? xa.z : xa.w;
            const float xs1 = (kk == 0) ? xb.x : (kk == 1) ? xb.y : (kk == 2) ? xb.z : xb.w;
            const float* wr = &Ws[(k0 + kk) * 64 + c0];
            const float4 w0 = *(const float4*)(wr);
            const float4 w1 = *(const float4*)(wr + 4);
            a00 = fmaf(xs0, w0.x, a00); a01 = fmaf(xs0, w0.y, a01);
            a02 = fmaf(xs0, w0.z, a02); a03 = fmaf(xs0, w0.w, a03);
            a04 = fmaf(xs0, w1.x, a04); a05 = fmaf(xs0, w1.y, a05);
            a06 = fmaf(xs0, w1.z, a06); a07 = fmaf(xs0, w1.w, a07);
            a10 = fmaf(xs1, w0.x, a10); a11 = fmaf(xs1, w0.y, a11);
            a12 = fmaf(xs1, w0.z, a12); a13 = fmaf(xs1, w0.w, a13);
            a14 = fmaf(xs1, w1.x, a14); a15 = fmaf(xs1, w1.y, a15);
            a16 = fmaf(xs1, w1.z, a16); a17 = fmaf(xs1, w1.w, a17);
        }
    }

    // pack 8 bf16 into 4 uints -> one 16B store per row
    if (v0) {
        uint4 p;
        p.x = (unsigned)f2bf(a00) | ((unsigned)f2bf(a01) << 16);
        p.y = (unsigned)f2bf(a02) | ((unsigned)f2bf(a03) << 16);
        p.z = (unsigned)f2bf(a04) | ((unsigned)f2bf(a05) << 16);
        p.w = (unsigned)f2bf(a06) | ((unsigned)f2bf(a07) << 16);
        *(uint4*)&H[(size_t)r0 * 64 + c0] = p;
    }
    if (v1) {
        uint4 p;
        p.x = (unsigned)f2bf(a10) | ((unsigned)f2bf(a11) << 16);
        p.y = (unsigned)f2bf(a12) | ((unsigned)f2bf(a13) << 16);
        p.z = (unsigned)f2bf(a14) | ((unsigned)f2bf(a15) << 16);
        p.w = (unsigned)f2bf(a16) | ((unsigned)f2bf(a17) << 16);
        *(uint4*)&H[(size_t)r1 * 64 + c0] = p;
    }
}

// ---------------- Aggregation core (bf16 H) ----------------
// One wave per node. Lanes = 4 edge-slots (g) x 16 channel-quads (c4).
// One VMEM instr gathers 4 edge-rows x 8B (bf16x4) = 2 cache lines/row.
// R5 model: agg is L2-miss-latency bound; bf16 H (6.4MB) ~fits per-XCD L2
// and halves line-touches -> FETCH and dur should drop ~40%.
// Dense math (acc, bias, ReLU, tail GEMM) stays fp32: one rounding/layer.

template <bool RELU>
__device__ __forceinline__ float4 agg_row(const unsigned short* __restrict__ H,
                                          const int* __restrict__ row_ptr,
                                          const long long* __restrict__ csr_ll,
                                          const float* __restrict__ dinv,
                                          const float* __restrict__ bias,
                                          int i, int lane, int g, int c4) {
    float4 acc = make_float4(0.f, 0.f, 0.f, 0.f);

    int start = row_ptr[i], end = row_ptr[i + 1];
    for (int base = start; base < end; base += 64) {
        int e = base + lane;
        long long pk = (e < end) ? __builtin_nontemporal_load(csr_ll + e) : 0LL;
        int px = (int)(pk & 0xffffffffLL);
        int py = (int)(pk >> 32);                 // norm bits (0 -> 0.0f)
        int m  = end - base; if (m > 64) m = 64;
        int nt = (m + 3) >> 2;
#pragma unroll 4
        for (int t = 0; t < nt; ++t) {
            int sl   = t * 4 + g;
            int ss   = __shfl(px, sl);
            float nn = __uint_as_float(__shfl(py, sl));
            ushort4 h = *(const ushort4*)&H[(size_t)ss * 64 + c4];
            acc.x = fmaf(bf2f(h.x), nn, acc.x);
            acc.y = fmaf(bf2f(h.y), nn, acc.y);
            acc.z = fmaf(bf2f(h.z), nn, acc.z);
            acc.w = fmaf(bf2f(h.w), nn, acc.w);
        }
    }

#pragma unroll
    for (int d = 16; d <= 32; d <<= 1) {
        acc.x += __shfl_xor(acc.x, d);
        acc.y += __shfl_xor(acc.y, d);
        acc.z += __shfl_xor(acc.z, d);
        acc.w += __shfl_xor(acc.w, d);
    }

    float di  = dinv[i];
    float sl2 = 2.0f * di * di;
    ushort4 hs = *(const ushort4*)&H[(size_t)i * 64 + c4];
    float4 b4  = *(const float4*)&bias[c4];
    float4 r;
    r.x = acc.x + sl2 * bf2f(hs.x) + b4.x;
    r.y = acc.y + sl2 * bf2f(hs.y) + b4.y;
    r.z = acc.z + sl2 * bf2f(hs.z) + b4.z;
    r.w = acc.w + sl2 * bf2f(hs.w) + b4.w;
    if (RELU) {
        r.x = fmaxf(r.x, 0.f); r.y = fmaxf(r.y, 0.f);
        r.z = fmaxf(r.z, 0.f); r.w = fmaxf(r.w, 0.f);
    }
    return r;
}

// Final layer: aggregation only (no ReLU), fp32 out (d_out).
__global__ __launch_bounds__(256, 4) void k_agg_last(const unsigned short* __restrict__ H,
                                                     const int* __restrict__ row_ptr,
                                                     const long long* __restrict__ csr_ll,
                                                     const float* __restrict__ dinv,
                                                     const float* __restrict__ bias,
                                                     float* __restrict__ out, int N) {
    int wid  = threadIdx.x >> 6;
    int lane = threadIdx.x & 63;
    int i = blockIdx.x * 4 + wid;
    if (i >= N) return;
    const int g  = lane >> 4;
    const int c4 = (lane & 15) * 4;
    float4 r = agg_row<false>(H, row_ptr, csr_ll, dinv, bias, i, lane, g, c4);
    if (g == 0)
        *(float4*)&out[(size_t)i * 64 + c4] = r;
}

// Fused: A = ReLU(S*H + b) (fp32) then tail-GEMM @ W_next (fp32), H_next bf16.
__global__ __launch_bounds__(256, 4) void k_fused(const unsigned short* __restrict__ H,
                                                  const int* __restrict__ row_ptr,
                                                  const long long* __restrict__ csr_ll,
                                                  const float* __restrict__ dinv,
                                                  const float* __restrict__ bias,
                                                  const float* __restrict__ Wn,
                                                  unsigned short* __restrict__ Hout, int N) {
    __shared__ float Wl[64 * 64];
    __shared__ float Al[4][64];

    for (int t = threadIdx.x; t < 1024; t += 256)
        ((float4*)Wl)[t] = ((const float4*)Wn)[t];
    __syncthreads();

    int wid  = threadIdx.x >> 6;
    int lane = threadIdx.x & 63;
    int i = blockIdx.x * 4 + wid;
    if (i >= N) return;
    const int g  = lane >> 4;
    const int c4 = (lane & 15) * 4;

    float4 r = agg_row<true>(H, row_ptr, csr_ll, dinv, bias, i, lane, g, c4);
    if (g == 0)
        *(float4*)&Al[wid][c4] = r;
    __syncthreads();

    float y = 0.0f;
#pragma unroll 4
    for (int c = 0; c < 64; c += 4) {
        float4 a = *(const float4*)&Al[wid][c];
        y = fmaf(a.x, Wl[(c + 0) * 64 + lane], y);
        y = fmaf(a.y, Wl[(c + 1) * 64 + lane], y);
        y = fmaf(a.z, Wl[(c + 2) * 64 + lane], y);
        y = fmaf(a.w, Wl[(c + 3) * 64 + lane], y);
    }
    Hout[(size_t)i * 64 + lane] = f2bf(y);
}

// ---------------- launch ----------------

extern "C" void kernel_launch(void* const* d_in, const int* in_sizes, int n_in,
                              void* d_out, int out_size, void* d_ws, size_t ws_size,
                              hipStream_t stream) {
    (void)in_sizes; (void)n_in; (void)out_size; (void)ws_size;

    const float* x  = (const float*)d_in[0];
    const int*   ei = (const int*)d_in[1];
    const float* Wl[5] = {(const float*)d_in[2], (const float*)d_in[4], (const float*)d_in[6],
                          (const float*)d_in[8], (const float*)d_in[10]};
    const float* bl[5] = {(const float*)d_in[3], (const float*)d_in[5], (const float*)d_in[7],
                          (const float*)d_in[9], (const float*)d_in[11]};
    float* out = (float*)d_out;

    const int* src = ei;
    const int* dst = ei + NE;

    char* ws = (char*)d_ws;
    size_t off = 0;
    auto alloc = [&](size_t bytes) -> void* {
        void* p = ws + off;
        off += (bytes + 255) & ~(size_t)255;
        return p;
    };
    int*   cnt      = (int*)alloc(NN * 4);
    int*   row_ptr  = (int*)alloc((NN + 1) * 4);
    int*   cursor   = (int*)alloc(NN * 4);
    int*   bsum     = (int*)alloc(256 * 4);
    float* dinv     = (float*)alloc(NN * 4);
    int2*  csr      = (int2*)alloc((size_t)NE * 8);
    unsigned short* Hb  = (unsigned short*)alloc((size_t)NN * 64 * 2);
    unsigned short* Hb2 = (unsigned short*)alloc((size_t)NN * 64 * 2);

    hipMemsetAsync(cnt, 0, NN * 4, stream);
    hipMemsetAsync(cursor, 0, NN * 4, stream);

    int ebl = (NE + 255) / 256;
    int nbl = (NN + 255) / 256;
    k_count<<<ebl, 256, 0, stream>>>(dst, cnt, NE);
    k_dinv<<<nbl, 256, 0, stream>>>(cnt, dinv, NN);
    k_scanA<<<nbl, 256, 0, stream>>>(cnt, row_ptr, bsum, NN);
    k_scanB<<<1, 256, 0, stream>>>(bsum, nbl);
    k_scanC<<<nbl, 256, 0, stream>>>(row_ptr, bsum, NN, NE);
    k_fill<<<ebl, 256, 0, stream>>>(src, dst, dinv, row_ptr, cursor, csr, NE);

    const long long* csr_ll = (const long long*)csr;
    int gg = (NN + 63) / 64;
    int ga = (NN + 3) / 4;

    // layer 1 GEMM (K=128) -> bf16 H
    k_gemm128<<<gg, 256, 0, stream>>>(x, Wl[0], Hb, NN);
    // fused: agg_t (+b_t, ReLU) then @W_{t+1} -> bf16 H
    k_fused<<<ga, 256, 0, stream>>>(Hb,  row_ptr, csr_ll, dinv, bl[0], Wl[1], Hb2, NN);
    k_fused<<<ga, 256, 0, stream>>>(Hb2, row_ptr, csr_ll, dinv, bl[1], Wl[2], Hb,  NN);
    k_fused<<<ga, 256, 0, stream>>>(Hb,  row_ptr, csr_ll, dinv, bl[2], Wl[3], Hb2, NN);
    k_fused<<<ga, 256, 0, stream>>>(Hb2, row_ptr, csr_ll, dinv, bl[3], Wl[4], Hb,  NN);
    // final aggregation (no ReLU) -> fp32 d_out
    k_agg_last<<<ga, 256, 0, stream>>>(Hb, row_ptr, csr_ll, dinv, bl[4], out, NN);
}